// Round 7
// baseline (111.525 us; speedup 1.0000x reference)
//
#include <hip/hip_runtime.h>

// GeneralizedRecallLoss — two-stage, disjoint-wave-slices, native-trans.
// scores (512, 8192) f32, k_vals (3,) i32, pos_num=16. Output: 1 f32 scalar.
//
// Stage 1 (negsum): grid 512 rows x 4 chunks, block 256 (4 waves).
//   Each WAVE owns a disjoint quarter-chunk (<=128 float4) and ALL 16 j's
//   (16 independent accumulator chains; every cache line fetched once per
//   block; nontemporal so single-use lines don't allocate in L2 and don't
//   force dirty-poison writebacks on the read path).
//   Per pair (t = (neg - pos[j] + 0.1)*10*log2e):
//     f(d) = ln2*max(t,0) + 0.1*[t>=0] + ln2*log2(1 + 2^min(-t,10t))
//   log-terms as a running product (one v_log per (lane,j) at the end;
//   8 factors in (1,2] -> prod <= 2^8, no overflow). [t>=0] counted with
//   ballot+popcount on the scalar pipe (wave-uniform SGPR accumulators).
// Stage 2 (finalize): (row,j) -> rank -> 3 recalls -> atomicAdd.

#define ROWS 512
#define COLS 8192
#define POSN 16
#define NK 3
#define NCHUNK 4
#define CHUNK_F4 511          // float4s per chunk ((8192-16)/4/4)

typedef float f32x4 __attribute__((ext_vector_type(4)));

__global__ __launch_bounds__(256, 5)
void negsum_kernel(const float* __restrict__ scores, float* __restrict__ ws)
{
    const int b     = blockIdx.x;
    const int row   = b >> 2;
    const int chunk = b & 3;
    const int wave  = threadIdx.x >> 6;
    const int lane  = threadIdx.x & 63;
    const float* rowp = scores + (size_t)row * COLS;

    const float C10 = 14.4269504089f;     // 10*log2(e)
    const float A0  = 1.44269504089f;     // 0.1*C10 (margin pre-folded)
    const float LN2 = 0.69314718055994531f;

    float p10[POSN];
#pragma unroll
    for (int j = 0; j < POSN; ++j)
        p10[j] = rowp[j] * C10;

    const f32x4* negs =
        reinterpret_cast<const f32x4*>(rowp + POSN) + (size_t)chunk * CHUNK_F4;

    // this wave's disjoint quarter: f4 indices [wave*128, wave*128+128)
    // (only wave 3, it 1, lane 63 is out of range: clamp addr, patch value)
    f32x4 v[2];
    bool valid[2];
#pragma unroll
    for (int it = 0; it < 2; ++it) {
        int f = wave * 128 + it * 64 + lane;
        valid[it] = (f < CHUNK_F4);
        v[it] = __builtin_nontemporal_load(negs + (valid[it] ? f : CHUNK_F4 - 1));
    }
#pragma unroll
    for (int it = 0; it < 2; ++it) {
        if (!valid[it]) {
            v[it].x = -1.0e30f; v[it].y = -1.0e30f;
            v[it].z = -1.0e30f; v[it].w = -1.0e30f;
        }
    }

    float prod[POSN], accM[POSN];
    int   nge[POSN];                      // wave-uniform (SGPR) counters
#pragma unroll
    for (int j = 0; j < POSN; ++j) { prod[j] = 1.0f; accM[j] = 0.0f; nge[j] = 0; }

#pragma unroll
    for (int it = 0; it < 2; ++it) {
        float a10[4];
        a10[0] = __fmaf_rn(v[it].x, C10, A0);
        a10[1] = __fmaf_rn(v[it].y, C10, A0);
        a10[2] = __fmaf_rn(v[it].z, C10, A0);
        a10[3] = __fmaf_rn(v[it].w, C10, A0);
#pragma unroll
        for (int e = 0; e < 4; ++e) {
#pragma unroll
            for (int j = 0; j < POSN; ++j) {
                const float t   = a10[e] - p10[j];
                const float arg = fminf(-t, 10.0f * t);        // -|scaled t|
                const float u   = __builtin_amdgcn_exp2f(arg); // (0,1]
                prod[j] = __fmaf_rn(prod[j], u, prod[j]);      // *= (1+u)
                accM[j] += fmaxf(t, 0.0f);
                nge[j] += (int)__popcll(__ballot(t >= 0.0f));  // scalar pipe
            }
        }
    }

    // partial = ln2*Σ(accM + log2 prod) + 0.1*nge   (pads contribute 0)
#pragma unroll
    for (int j = 0; j < POSN; ++j) {
        float s = accM[j] + __builtin_amdgcn_logf(prod[j]);
#pragma unroll
        for (int off = 32; off > 0; off >>= 1)
            s += __shfl_xor(s, off);
        if (lane == 0) {
            s = __fmaf_rn(s, LN2, 0.1f * (float)nge[j]);
            ws[(((size_t)chunk * ROWS + row) * POSN + j) * 4 + wave] = s;
        }
    }
}

__global__ __launch_bounds__(256)
void finalize_kernel(const float* __restrict__ scores,
                     const float* __restrict__ ws,
                     const int* __restrict__ k_vals,
                     float* __restrict__ out)
{
    const int gid = blockIdx.x * 256 + threadIdx.x;   // 0..8191
    const int row = gid >> 4;
    const int j   = gid & 15;
    const float* rowp = scores + (size_t)row * COLS;

    float negsum = 0.0f;
#pragma unroll
    for (int c = 0; c < NCHUNK; ++c)
#pragma unroll
        for (int w = 0; w < 4; ++w)
            negsum += ws[(((size_t)c * ROWS + row) * POSN + j) * 4 + w];

    const float pj = rowp[j];
    float cnt = -1.0f;                    // remove the i==j diagonal
#pragma unroll
    for (int i = 0; i < POSN; ++i)
        cnt += (rowp[i] >= pj) ? 1.0f : 0.0f;

    const float rank = 1.0f + cnt + negsum;

    float rsum = 0.0f;
#pragma unroll
    for (int k = 0; k < NK; ++k) {
        float z = (rank - (float)k_vals[k]) * 10.0f;
        z = fminf(z, 88.0f);
        const float e2 = __builtin_amdgcn_exp2f(-1.44269504089f * fabsf(z));
        rsum += fmaxf(z, 0.0f)
              + 0.69314718056f * __builtin_amdgcn_logf(1.0f + e2);
    }

    const int wave = threadIdx.x >> 6;
    const int lane = threadIdx.x & 63;
#pragma unroll
    for (int off = 32; off > 0; off >>= 1)
        rsum += __shfl_xor(rsum, off);

    __shared__ float sp[4];
    if (lane == 0) sp[wave] = rsum;
    __syncthreads();
    if (threadIdx.x == 0) {
        const float s = sp[0] + sp[1] + sp[2] + sp[3];
        atomicAdd(out, s * (1.0f / ((float)POSN * (float)NK * (float)ROWS)));
    }
}

extern "C" void kernel_launch(void* const* d_in, const int* in_sizes, int n_in,
                              void* d_out, int out_size, void* d_ws, size_t ws_size,
                              hipStream_t stream) {
    const float* scores = (const float*)d_in[0];
    const int*   k_vals = (const int*)d_in[1];
    float* out = (float*)d_out;
    float* ws  = (float*)d_ws;   // 4*512*16*4 f32 = 512 KB partial neg-sums

    hipMemsetAsync(out, 0, sizeof(float), stream);
    negsum_kernel<<<ROWS * NCHUNK, 256, 0, stream>>>(scores, ws);
    finalize_kernel<<<(ROWS * POSN) / 256, 256, 0, stream>>>(scores, ws, k_vals, out);
}